// Round 8
// baseline (641.081 us; speedup 1.0000x reference)
//
#include <hip/hip_runtime.h>
#include <hip/hip_bf16.h>

#define N_NODES 50000
#define N_EDGES 800000
#define DIM 128
#define NREL 8
#define KTOT 1152              // (NREL+1)*DIM
#define NRSEG (N_NODES * NREL) // 400000
#define BN_EPS 1e-5f
#define KSPLIT 576             // KTOT/2
#define LDSTRIDE 36            // padded LDS row stride in elems (72 B -> 2-way, free)

typedef __attribute__((ext_vector_type(8))) short bf16x8;
typedef __attribute__((ext_vector_type(16))) float f32x16;

__device__ inline float b2f(short s) {
    union { unsigned u; float f; } t;
    t.u = ((unsigned)(unsigned short)s) << 16;
    return t.f;
}
__device__ inline short f2b(float f) {
    __hip_bfloat16 h = __float2bfloat16(f);
    return *reinterpret_cast<short*>(&h);
}
__device__ inline void acc4(float4& s, const float4& v) {
    s.x += v.x; s.y += v.y; s.z += v.z; s.w += v.w;
}

// ---------------- CSR build ----------------

__global__ void k_hist(const int* __restrict__ ei, const int* __restrict__ et,
                       int* __restrict__ cnt) {
    int e = blockIdx.x * 256 + threadIdx.x;
    if (e < N_EDGES) {
        int tgt = ei[N_EDGES + e];
        int r = et[e];
        atomicAdd(&cnt[tgt * NREL + r], 1);
    }
}

__global__ void k_alloc(const int* __restrict__ cnt, int* __restrict__ offs,
                        int* __restrict__ cursor) {
    int i = blockIdx.x * 256 + threadIdx.x;
    int lane = threadIdx.x & 63;
    int c = (i < NRSEG) ? cnt[i] : 0;
    int incl = c;
    #pragma unroll
    for (int d = 1; d < 64; d <<= 1) {
        int t = __shfl_up(incl, d, 64);
        if (lane >= d) incl += t;
    }
    int total = __shfl(incl, 63, 64);
    int base = 0;
    if (lane == 63) base = atomicAdd(cursor, total);
    base = __shfl(base, 63, 64);
    if (i < NRSEG) offs[i] = base + incl - c;
}

__global__ void k_fill(const int* __restrict__ ei, const int* __restrict__ et,
                       const int* __restrict__ offs, int* __restrict__ fillcur,
                       int* __restrict__ sorted) {
    int e = blockIdx.x * 256 + threadIdx.x;
    if (e < N_EDGES) {
        int src = ei[e];
        int tgt = ei[N_EDGES + e];
        int comp = tgt * NREL + et[e];
        int pos = atomicAdd(&fillcur[comp], 1);
        sorted[offs[comp] + pos] = src;
    }
}

// ---------------- weight conversion (both layers in one launch)
__global__ void k_wconv2(const float* __restrict__ W1, const float* __restrict__ root1,
                         __hip_bfloat16* __restrict__ Bt1,
                         const float* __restrict__ W2, const float* __restrict__ root2,
                         __hip_bfloat16* __restrict__ Bt2) {
    int gidx = blockIdx.x * 256 + threadIdx.x;
    int which = gidx >= DIM * KTOT;
    int idx = which ? gidx - DIM * KTOT : gidx;
    const float* W = which ? W2 : W1;
    const float* root = which ? root2 : root1;
    __hip_bfloat16* Bt = which ? Bt2 : Bt1;
    int o = idx / KTOT, k = idx % KTOT;
    float v;
    if (k < NREL * DIM) {
        int r = k >> 7, i = k & 127;
        v = W[(r * DIM + i) * DIM + o];
    } else {
        int i = k - NREL * DIM;
        v = root[i * DIM + o];
    }
    Bt[idx] = __float2bfloat16(v);
}

// ---------------- buildA3: fp32 gather (unchanged from R7)
__global__ __launch_bounds__(256) void k_buildA3(
        const float* __restrict__ xr,
        const int* __restrict__ cnt, const int* __restrict__ offs,
        const int* __restrict__ sorted,
        __hip_bfloat16* __restrict__ A) {
    int tid = threadIdx.x;
    int unit = tid >> 5, il = tid & 31;
    int node = blockIdx.x * 8 + unit;
    if (node >= N_NODES) return;
    int ch = il * 4;
    int c = 0, o = 0;
    if (il < 8) {
        c = cnt[node * NREL + il];
        o = offs[node * NREL + il];
    }
    int ubase = (tid & 63) & 32;
    int c8[8], o8[8];
    #pragma unroll
    for (int r = 0; r < 8; ++r) {
        c8[r] = __shfl(c, ubase + r, 64);
        o8[r] = __shfl(o, ubase + r, 64);
    }
    const float* xch = xr + ch;
    __hip_bfloat16* arow = A + (size_t)node * KTOT + ch;

    #pragma unroll
    for (int rp = 0; rp < 4; ++rp) {
        int ca = c8[2 * rp], oa = o8[2 * rp];
        int cb = c8[2 * rp + 1], ob = o8[2 * rp + 1];
        float4 s0 = {0.f, 0.f, 0.f, 0.f}, s1 = {0.f, 0.f, 0.f, 0.f};
        int mx = max(ca, cb);
        for (int i = 0; i < mx; i += 2) {
            int ia0 = (i < ca) ? sorted[oa + i] : -1;
            int ia1 = (i + 1 < ca) ? sorted[oa + i + 1] : -1;
            int ib0 = (i < cb) ? sorted[ob + i] : -1;
            int ib1 = (i + 1 < cb) ? sorted[ob + i + 1] : -1;
            float4 va0 = {0,0,0,0}, va1 = {0,0,0,0}, vb0 = {0,0,0,0}, vb1 = {0,0,0,0};
            if (ia0 >= 0) va0 = *(const float4*)(xch + (size_t)ia0 * DIM);
            if (ia1 >= 0) va1 = *(const float4*)(xch + (size_t)ia1 * DIM);
            if (ib0 >= 0) vb0 = *(const float4*)(xch + (size_t)ib0 * DIM);
            if (ib1 >= 0) vb1 = *(const float4*)(xch + (size_t)ib1 * DIM);
            acc4(s0, va0); acc4(s0, va1);
            acc4(s1, vb0); acc4(s1, vb1);
        }
        float inva = (ca > 0) ? 1.f / (float)ca : 0.f;
        float invb = (cb > 0) ? 1.f / (float)cb : 0.f;
        short4 outa, outb;
        outa.x = f2b(s0.x * inva); outa.y = f2b(s0.y * inva);
        outa.z = f2b(s0.z * inva); outa.w = f2b(s0.w * inva);
        outb.x = f2b(s1.x * invb); outb.y = f2b(s1.y * invb);
        outb.z = f2b(s1.z * invb); outb.w = f2b(s1.w * invb);
        *(short4*)(arow + (2 * rp) * DIM) = outa;
        *(short4*)(arow + (2 * rp + 1) * DIM) = outb;
    }
    float4 sv = *(const float4*)(xch + (size_t)node * DIM);
    short4 so;
    so.x = f2b(sv.x); so.y = f2b(sv.y); so.z = f2b(sv.z); so.w = f2b(sv.w);
    *(short4*)(arow + NREL * DIM) = so;
}

// ---------------- GEMM v6: LDS-staged 128x128 tile, K-split 2, double-buffered.
// Staging is COALESCED: thread t loads row t/4, 16B slot t&3 -> each wave
// instruction touches 16 fully-used 64B lines (vs 32 half-lines when each
// lane owns a row). Reg-staged (global->VGPR->ds_write) so the LDS row
// stride can be padded to 36 elems (72 B): bank rotation 18 -> 2-way (free).
// 4 waves x (64 rows x 64 cols); mfma_f32_32x32x16_bf16 from LDS.
// One barrier per 32-K chunk; next chunk's loads issued before MFMA.
// Output: fp32 partial p[ks][N][DIM] (bias/stats applied in k_fin).
__global__ __launch_bounds__(256) void k_gemm6(
        const __hip_bfloat16* __restrict__ A,
        const __hip_bfloat16* __restrict__ Bt,
        float* __restrict__ p) {
    __shared__ __hip_bfloat16 As[2][128 * LDSTRIDE];
    __shared__ __hip_bfloat16 Bs[2][128 * LDSTRIDE];
    int tid = threadIdx.x;
    int rt = blockIdx.x >> 1, ks = blockIdx.x & 1;
    int m0 = rt * 128;
    int kbase = ks * KSPLIT;
    float* pout = p + (size_t)ks * N_NODES * DIM;

    // staging indices: thread t -> rows {srow, srow+64}, slot sslot
    int srow = tid >> 2, sslot = tid & 3;
    int arow0 = m0 + srow;      if (arow0 >= N_NODES) arow0 = N_NODES - 1;
    int arow1 = m0 + 64 + srow; if (arow1 >= N_NODES) arow1 = N_NODES - 1;
    const __hip_bfloat16* aSrc0 = A + (size_t)arow0 * KTOT + kbase + sslot * 8;
    const __hip_bfloat16* aSrc1 = A + (size_t)arow1 * KTOT + kbase + sslot * 8;
    const __hip_bfloat16* bSrc0 = Bt + (size_t)srow * KTOT + kbase + sslot * 8;
    const __hip_bfloat16* bSrc1 = Bt + (size_t)(64 + srow) * KTOT + kbase + sslot * 8;
    int lds0 = srow * LDSTRIDE + sslot * 8;
    int lds1 = (64 + srow) * LDSTRIDE + sslot * 8;

    // mfma indices: wave (wr,wc) owns rows wr*64+[0,64), cols wc*64+[0,64)
    int lane = tid & 63, wid = tid >> 6;
    int wr = wid >> 1, wc = wid & 1;
    int half = lane >> 5, l31 = lane & 31;
    f32x16 acc00 = {}, acc01 = {}, acc10 = {}, acc11 = {};

    // preload chunk 0
    bf16x8 la0 = *(const bf16x8*)aSrc0;
    bf16x8 la1 = *(const bf16x8*)aSrc1;
    bf16x8 lb0 = *(const bf16x8*)bSrc0;
    bf16x8 lb1 = *(const bf16x8*)bSrc1;
    *(bf16x8*)&As[0][lds0] = la0;
    *(bf16x8*)&As[0][lds1] = la1;
    *(bf16x8*)&Bs[0][lds0] = lb0;
    *(bf16x8*)&Bs[0][lds1] = lb1;
    __syncthreads();

    #pragma unroll 1
    for (int t = 0; t < KSPLIT / 32; ++t) {
        int cur = t & 1;
        if (t < KSPLIT / 32 - 1) {
            int ko = (t + 1) * 32;
            la0 = *(const bf16x8*)(aSrc0 + ko);
            la1 = *(const bf16x8*)(aSrc1 + ko);
            lb0 = *(const bf16x8*)(bSrc0 + ko);
            lb1 = *(const bf16x8*)(bSrc1 + ko);
        }
        const __hip_bfloat16* as = As[cur];
        const __hip_bfloat16* bs = Bs[cur];
        #pragma unroll
        for (int s = 0; s < 2; ++s) {
            int slot = (s * 2 + half) * 8;
            bf16x8 a0 = *(const bf16x8*)&as[(wr * 64 + l31) * LDSTRIDE + slot];
            bf16x8 a1 = *(const bf16x8*)&as[(wr * 64 + 32 + l31) * LDSTRIDE + slot];
            bf16x8 b0 = *(const bf16x8*)&bs[(wc * 64 + l31) * LDSTRIDE + slot];
            bf16x8 b1 = *(const bf16x8*)&bs[(wc * 64 + 32 + l31) * LDSTRIDE + slot];
            acc00 = __builtin_amdgcn_mfma_f32_32x32x16_bf16(a0, b0, acc00, 0, 0, 0);
            acc01 = __builtin_amdgcn_mfma_f32_32x32x16_bf16(a0, b1, acc01, 0, 0, 0);
            acc10 = __builtin_amdgcn_mfma_f32_32x32x16_bf16(a1, b0, acc10, 0, 0, 0);
            acc11 = __builtin_amdgcn_mfma_f32_32x32x16_bf16(a1, b1, acc11, 0, 0, 0);
        }
        if (t < KSPLIT / 32 - 1) {
            int nxt = cur ^ 1;
            *(bf16x8*)&As[nxt][lds0] = la0;
            *(bf16x8*)&As[nxt][lds1] = la1;
            *(bf16x8*)&Bs[nxt][lds0] = lb0;
            *(bf16x8*)&Bs[nxt][lds1] = lb1;
        }
        __syncthreads();
    }

    // epilogue: write fp32 partials
    #pragma unroll
    for (int m = 0; m < 2; ++m) {
        const f32x16& am0 = m ? acc10 : acc00;
        const f32x16& am1 = m ? acc11 : acc01;
        #pragma unroll
        for (int reg = 0; reg < 16; ++reg) {
            int row = m0 + wr * 64 + m * 32 + (reg & 3) + 8 * (reg >> 2) + 4 * half;
            if (row < N_NODES) {
                pout[(size_t)row * DIM + wc * 64 + l31]      = am0[reg];
                pout[(size_t)row * DIM + wc * 64 + 32 + l31] = am1[reg];
            }
        }
    }
}

// ---------------- finalize: h = p0 + p1 + bias (bf16), BN stats atomics
__global__ void k_fin(const float* __restrict__ p, const float* __restrict__ bias,
                      __hip_bfloat16* __restrict__ h, float* __restrict__ stats) {
    int c = threadIdx.x & 127;
    int half = threadIdx.x >> 7;
    const float* p1 = p + (size_t)N_NODES * DIM;
    float bv = bias[c];
    float s = 0.f, q = 0.f;
    for (int v = blockIdx.x * 2 + half; v < N_NODES; v += gridDim.x * 2) {
        size_t idx = (size_t)v * DIM + c;
        float x = p[idx] + p1[idx] + bv;
        h[idx] = __float2bfloat16(x);
        s += x; q += x * x;
    }
    __shared__ float ls[256], lq[256];
    ls[threadIdx.x] = s; lq[threadIdx.x] = q;
    __syncthreads();
    if (half == 0) {
        s += ls[c + 128]; q += lq[c + 128];
        atomicAdd(&stats[c], s);
        atomicAdd(&stats[128 + c], q);
    }
}

// ---------------- castbn: xr = relu(bn(h)) fp32; bn derived inline from stats
__global__ void k_castbn(const __hip_bfloat16* __restrict__ h, const float* __restrict__ stats,
                         const float* __restrict__ g, const float* __restrict__ be,
                         float* __restrict__ xr) {
    int i = (blockIdx.x * 256 + threadIdx.x) * 8;
    if (i >= N_NODES * DIM) return;
    int ch = i & 127;
    bf16x8 v = *(const bf16x8*)&h[i];
    const float invn = 1.f / (float)N_NODES;
    float o[8];
    #pragma unroll
    for (int j = 0; j < 8; ++j) {
        float m = stats[ch + j] * invn;
        float var = stats[128 + ch + j] * invn - m * m;
        float a = g[ch + j] * rsqrtf(var + BN_EPS);
        float b = be[ch + j] - m * a;
        o[j] = fmaxf(b2f(v[j]) * a + b, 0.f);
    }
    float4 o0 = {o[0], o[1], o[2], o[3]};
    float4 o1 = {o[4], o[5], o[6], o[7]};
    *(float4*)&xr[i] = o0;
    *(float4*)&xr[i + 4] = o1;
}

// ---------------- classifier: out[v,0:2] = relu(bn(h2[v])) @ cw + cb, bn inline
__global__ void k_classifier(const __hip_bfloat16* __restrict__ h, const float* __restrict__ stats,
                             const float* __restrict__ g, const float* __restrict__ be,
                             const float* __restrict__ cw, const float* __restrict__ cb,
                             float* __restrict__ out) {
    int w = blockIdx.x * 4 + (threadIdx.x >> 6);
    int lane = threadIdx.x & 63;
    if (w >= N_NODES) return;
    int c = lane * 2;
    const float invn = 1.f / (float)N_NODES;
    __hip_bfloat162 hv = *(const __hip_bfloat162*)&h[(size_t)w * DIM + c];
    float m0 = stats[c] * invn, var0 = stats[128 + c] * invn - m0 * m0;
    float a0 = g[c] * rsqrtf(var0 + BN_EPS), b0 = be[c] - m0 * a0;
    float m1 = stats[c + 1] * invn, var1 = stats[128 + c + 1] * invn - m1 * m1;
    float a1 = g[c + 1] * rsqrtf(var1 + BN_EPS), b1 = be[c + 1] - m1 * a1;
    float p0 = fmaxf(__bfloat162float(hv.x) * a0 + b0, 0.f);
    float p1 = fmaxf(__bfloat162float(hv.y) * a1 + b1, 0.f);
    float acc0 = p0 * cw[c * 2] + p1 * cw[(c + 1) * 2];
    float acc1 = p0 * cw[c * 2 + 1] + p1 * cw[(c + 1) * 2 + 1];
    #pragma unroll
    for (int d = 32; d; d >>= 1) {
        acc0 += __shfl_down(acc0, d, 64);
        acc1 += __shfl_down(acc1, d, 64);
    }
    if (lane == 0) {
        out[w * 2] = acc0 + cb[0];
        out[w * 2 + 1] = acc1 + cb[1];
    }
}

extern "C" void kernel_launch(void* const* d_in, const int* in_sizes, int n_in,
                              void* d_out, int out_size, void* d_ws, size_t ws_size,
                              hipStream_t stream) {
    const float* x    = (const float*)d_in[0];
    const int*   ei   = (const int*)d_in[1];
    const int*   et   = (const int*)d_in[2];
    const float* w1   = (const float*)d_in[3];
    const float* root1= (const float*)d_in[4];
    const float* b1   = (const float*)d_in[5];
    const float* g1   = (const float*)d_in[6];
    const float* be1  = (const float*)d_in[7];
    const float* w2   = (const float*)d_in[8];
    const float* root2= (const float*)d_in[9];
    const float* b2   = (const float*)d_in[10];
    const float* g2   = (const float*)d_in[11];
    const float* be2  = (const float*)d_in[12];
    const float* cw   = (const float*)d_in[13];
    const float* cb   = (const float*)d_in[14];
    float* out = (float*)d_out;

    char* ws = (char*)d_ws;
    size_t off = 0;
    auto alloc = [&](size_t bytes) -> char* {
        char* p = ws + off;
        off += (bytes + 255) & ~(size_t)255;
        return p;
    };
    // zeroed region first
    int*   cnt     = (int*)alloc((size_t)NRSEG * 4);
    int*   fillcur = (int*)alloc((size_t)NRSEG * 4);
    int*   cursor  = (int*)alloc(256);
    float* stats1  = (float*)alloc(1024);
    float* stats2  = (float*)alloc(1024);
    size_t zero_bytes = off;
    int*   offs    = (int*)alloc((size_t)NRSEG * 4);
    __hip_bfloat16* Bt1 = (__hip_bfloat16*)alloc((size_t)DIM * KTOT * 2);
    __hip_bfloat16* Bt2 = (__hip_bfloat16*)alloc((size_t)DIM * KTOT * 2);
    int*   sorted  = (int*)alloc((size_t)N_EDGES * 4);
    float* p       = (float*)alloc((size_t)2 * N_NODES * DIM * 4);  // 51.2 MB
    float* xr      = p;                                             // aliases p (dead after k_fin)
    __hip_bfloat16* h1 = (__hip_bfloat16*)alloc((size_t)N_NODES * DIM * 2);
    __hip_bfloat16* h2 = (__hip_bfloat16*)alloc((size_t)N_NODES * DIM * 2);
    __hip_bfloat16* A  = (__hip_bfloat16*)alloc((size_t)N_NODES * KTOT * 2);

    hipMemsetAsync(d_ws, 0, zero_bytes, stream);

    k_hist<<<(N_EDGES + 255) / 256, 256, 0, stream>>>(ei, et, cnt);
    k_alloc<<<(NRSEG + 255) / 256, 256, 0, stream>>>(cnt, offs, cursor);
    k_fill<<<(N_EDGES + 255) / 256, 256, 0, stream>>>(ei, et, offs, fillcur, sorted);
    k_wconv2<<<2 * DIM * KTOT / 256, 256, 0, stream>>>(w1, root1, Bt1, w2, root2, Bt2);

    int bA_grid = (N_NODES + 7) / 8;              // 6250
    int gemm_grid = ((N_NODES + 127) / 128) * 2;  // 391 row-tiles x 2 K-splits = 782

    // layer 1
    k_buildA3<<<bA_grid, 256, 0, stream>>>(x, cnt, offs, sorted, A);
    k_gemm6<<<gemm_grid, 256, 0, stream>>>(A, Bt1, p);
    k_fin<<<256, 256, 0, stream>>>(p, b1, h1, stats1);
    k_castbn<<<(N_NODES * DIM / 8 + 255) / 256, 256, 0, stream>>>(h1, stats1, g1, be1, xr);

    // layer 2
    k_buildA3<<<bA_grid, 256, 0, stream>>>(xr, cnt, offs, sorted, A);
    k_gemm6<<<gemm_grid, 256, 0, stream>>>(A, Bt2, p);
    k_fin<<<256, 256, 0, stream>>>(p, b2, h2, stats2);

    k_classifier<<<(N_NODES + 3) / 4, 256, 0, stream>>>(h2, stats2, g2, be2, cw, cb, out);
}

// Round 10
// 518.522 us; speedup vs baseline: 1.2364x; 1.2364x over previous
//
#include <hip/hip_runtime.h>
#include <hip/hip_bf16.h>

#define N_NODES 50000
#define N_EDGES 800000
#define DIM 128
#define NREL 8
#define KTOT 1152              // (NREL+1)*DIM
#define NRSEG (N_NODES * NREL) // 400000
#define BN_EPS 1e-5f
#define TILE 32                // nodes per block
#define ASTRIDE 136            // LDS row stride elems (272 B = 17 bank-quads -> conflict floor)

typedef __attribute__((ext_vector_type(8))) short bf16x8;
typedef __attribute__((ext_vector_type(16))) float f32x16;

__device__ inline float b2f(short s) {
    union { unsigned u; float f; } t;
    t.u = ((unsigned)(unsigned short)s) << 16;
    return t.f;
}
__device__ inline short f2b(float f) {
    __hip_bfloat16 h = __float2bfloat16(f);
    return *reinterpret_cast<short*>(&h);
}

// ---------------- CSR build ----------------

__global__ void k_hist(const int* __restrict__ ei, const int* __restrict__ et,
                       int* __restrict__ cnt) {
    int e = blockIdx.x * 256 + threadIdx.x;
    if (e < N_EDGES) {
        int tgt = ei[N_EDGES + e];
        int r = et[e];
        atomicAdd(&cnt[tgt * NREL + r], 1);
    }
}

__global__ void k_alloc(const int* __restrict__ cnt, int* __restrict__ offs,
                        int* __restrict__ cursor) {
    int i = blockIdx.x * 256 + threadIdx.x;
    int lane = threadIdx.x & 63;
    int c = (i < NRSEG) ? cnt[i] : 0;
    int incl = c;
    #pragma unroll
    for (int d = 1; d < 64; d <<= 1) {
        int t = __shfl_up(incl, d, 64);
        if (lane >= d) incl += t;
    }
    int total = __shfl(incl, 63, 64);
    int base = 0;
    if (lane == 63) base = atomicAdd(cursor, total);
    base = __shfl(base, 63, 64);
    if (i < NRSEG) offs[i] = base + incl - c;
}

__global__ void k_fill(const int* __restrict__ ei, const int* __restrict__ et,
                       const int* __restrict__ offs, int* __restrict__ fillcur,
                       int* __restrict__ sorted) {
    int e = blockIdx.x * 256 + threadIdx.x;
    if (e < N_EDGES) {
        int src = ei[e];
        int tgt = ei[N_EDGES + e];
        int comp = tgt * NREL + et[e];
        int pos = atomicAdd(&fillcur[comp], 1);
        sorted[offs[comp] + pos] = src;
    }
}

// ---------------- weight conversion (both layers in one launch)
__global__ void k_wconv2(const float* __restrict__ W1, const float* __restrict__ root1,
                         __hip_bfloat16* __restrict__ Bt1,
                         const float* __restrict__ W2, const float* __restrict__ root2,
                         __hip_bfloat16* __restrict__ Bt2) {
    int gidx = blockIdx.x * 256 + threadIdx.x;
    int which = gidx >= DIM * KTOT;
    int idx = which ? gidx - DIM * KTOT : gidx;
    const float* W = which ? W2 : W1;
    const float* root = which ? root2 : root1;
    __hip_bfloat16* Bt = which ? Bt2 : Bt1;
    int o = idx / KTOT, k = idx % KTOT;
    float v;
    if (k < NREL * DIM) {
        int r = k >> 7, i = k & 127;
        v = W[(r * DIM + i) * DIM + o];
    } else {
        int i = k - NREL * DIM;
        v = root[i * DIM + o];
    }
    Bt[idx] = __float2bfloat16(v);
}

// ---------------- cast fp32 input -> bf16
__global__ void k_cast(const float* __restrict__ in, __hip_bfloat16* __restrict__ out) {
    int i = (blockIdx.x * 256 + threadIdx.x) * 4;
    if (i >= N_NODES * DIM) return;
    float4 v = *(const float4*)&in[i];
    short4 o;
    o.x = f2b(v.x); o.y = f2b(v.y); o.z = f2b(v.z); o.w = f2b(v.w);
    *(short4*)&out[i] = o;
}

// ---------------- castbn2: xb = bf16(relu(bn(h))), bn derived inline from stats
__global__ void k_castbn2(const __hip_bfloat16* __restrict__ h, const float* __restrict__ stats,
                          const float* __restrict__ g, const float* __restrict__ be,
                          __hip_bfloat16* __restrict__ xb) {
    int i = (blockIdx.x * 256 + threadIdx.x) * 8;
    if (i >= N_NODES * DIM) return;
    int ch = i & 127;
    bf16x8 v = *(const bf16x8*)&h[i];
    const float invn = 1.f / (float)N_NODES;
    bf16x8 o;
    #pragma unroll
    for (int j = 0; j < 8; ++j) {
        float m = stats[ch + j] * invn;
        float var = stats[128 + ch + j] * invn - m * m;
        float a = g[ch + j] * rsqrtf(var + BN_EPS);
        float b = be[ch + j] - m * a;
        o[j] = f2b(fmaxf(b2f(v[j]) * a + b, 0.f));
    }
    *(bf16x8*)&xb[i] = o;
}

// ---------------- fused RGCN layer (v3): 32-node tile, 1563 blocks (~6/CU).
// Per K-slice r (8 relations + self): stage mean-tile At[32][128] bf16 into
// LDS (16 threads/node x 8 ch each; coalesced 16B reads of xb rows), barrier,
// then 4 waves x (32 rows x 32 cols) MFMA vs L2-resident Bt, barrier.
// LDS row stride 136 elems (17 bank-quads): ds_read_b128 at the 4-clk floor.
// Epilogue: bias, bf16 h write, BN-stat atomics.
// MFMA 32x32x16: A-frag lane l: row=l&31, k=(l>>5)*8+j; B-frag: col=l&31,
// same k. C/D: col=lane&31, row=(reg&3)+8*(reg>>2)+4*(lane>>5).
__global__ __launch_bounds__(256) void k_fusedC(
        const __hip_bfloat16* __restrict__ xb,
        const int* __restrict__ cnt, const int* __restrict__ offs,
        const int* __restrict__ sorted,
        const __hip_bfloat16* __restrict__ Bt,
        const float* __restrict__ bias,
        __hip_bfloat16* __restrict__ h, float* __restrict__ stats) {
    __shared__ __hip_bfloat16 At[TILE * ASTRIDE];   // 8704 B
    __shared__ int cntS[TILE][NREL];                // 1 KB
    __shared__ int offS[TILE][NREL];                // 1 KB
    int tid = threadIdx.x;
    int n0 = blockIdx.x * TILE;

    // ---- load CSR meta: thread t -> node t>>3, rel t&7
    {
        int ni = tid >> 3, r = tid & 7;
        int node = n0 + ni;
        int c = 0, o = 0;
        if (node < N_NODES) {
            c = cnt[node * NREL + r];
            o = offs[node * NREL + r];
        }
        cntS[ni][r] = c;
        offS[ni][r] = o;
    }
    __syncthreads();

    // mfma role indices
    int lane = tid & 63, wid = tid >> 6;
    int half = lane >> 5, l31 = lane & 31;
    const __hip_bfloat16* bBase = Bt + (size_t)(wid * 32 + l31) * KTOT + half * 8;
    f32x16 acc = {};

    // stage role indices: 2 passes of 16 nodes; 16 threads/node, 8 ch each
    int spn = tid >> 4;           // 0..15: node index within pass
    int sub = tid & 15;           // channel group: ch = sub*8
    const __hip_bfloat16* xsub = xb + sub * 8;

    #pragma unroll 1
    for (int r = 0; r < 9; ++r) {
        // ---- stage phase
        #pragma unroll
        for (int p = 0; p < 2; ++p) {
            int ni = p * 16 + spn;
            if (r < 8) {
                int c = cntS[ni][r];
                int o = offS[ni][r];
                float s[8] = {0.f,0.f,0.f,0.f,0.f,0.f,0.f,0.f};
                for (int i = 0; i < c; ++i) {
                    int idx = sorted[o + i];
                    bf16x8 rv = *(const bf16x8*)(xsub + (size_t)idx * DIM);
                    #pragma unroll
                    for (int j = 0; j < 8; ++j) s[j] += b2f(rv[j]);
                }
                float inv = (c > 0) ? 1.f / (float)c : 0.f;
                bf16x8 ov;
                #pragma unroll
                for (int j = 0; j < 8; ++j) ov[j] = f2b(s[j] * inv);
                *(bf16x8*)&At[ni * ASTRIDE + sub * 8] = ov;
            } else {
                int node = n0 + ni;
                bf16x8 sv = {};
                if (node < N_NODES) sv = *(const bf16x8*)(xsub + (size_t)node * DIM);
                *(bf16x8*)&At[ni * ASTRIDE + sub * 8] = sv;
            }
        }
        __syncthreads();
        // ---- mfma phase: K=128 slice r; wave wid owns cols wid*32..+32
        const __hip_bfloat16* bs = bBase + r * DIM;
        #pragma unroll
        for (int m = 0; m < 8; ++m) {
            bf16x8 a = *(const bf16x8*)&At[l31 * ASTRIDE + m * 16 + half * 8];
            bf16x8 b = *(const bf16x8*)(bs + m * 16);
            acc = __builtin_amdgcn_mfma_f32_32x32x16_bf16(a, b, acc, 0, 0, 0);
        }
        __syncthreads();
    }

    // ---- epilogue: bias, store h (bf16), BN stats
    int col = wid * 32 + l31;
    float bv = bias[col];
    float s1 = 0.f, s2 = 0.f;
    #pragma unroll
    for (int reg = 0; reg < 16; ++reg) {
        int row = n0 + (reg & 3) + 8 * (reg >> 2) + 4 * half;
        float v = acc[reg] + bv;
        if (row < N_NODES) {
            h[(size_t)row * DIM + col] = __float2bfloat16(v);
            s1 += v; s2 += v * v;
        }
    }
    s1 += __shfl_xor(s1, 32, 64);
    s2 += __shfl_xor(s2, 32, 64);
    if (half == 0) {
        atomicAdd(&stats[col], s1);
        atomicAdd(&stats[128 + col], s2);
    }
}

// ---------------- classifier: out[v,0:2] = relu(bn(h2[v])) @ cw + cb, bn inline
__global__ void k_classifier(const __hip_bfloat16* __restrict__ h, const float* __restrict__ stats,
                             const float* __restrict__ g, const float* __restrict__ be,
                             const float* __restrict__ cw, const float* __restrict__ cb,
                             float* __restrict__ out) {
    int w = blockIdx.x * 4 + (threadIdx.x >> 6);
    int lane = threadIdx.x & 63;
    if (w >= N_NODES) return;
    int c = lane * 2;
    const float invn = 1.f / (float)N_NODES;
    __hip_bfloat162 hv = *(const __hip_bfloat162*)&h[(size_t)w * DIM + c];
    float m0 = stats[c] * invn, var0 = stats[128 + c] * invn - m0 * m0;
    float a0 = g[c] * rsqrtf(var0 + BN_EPS), b0 = be[c] - m0 * a0;
    float m1 = stats[c + 1] * invn, var1 = stats[128 + c + 1] * invn - m1 * m1;
    float a1 = g[c + 1] * rsqrtf(var1 + BN_EPS), b1 = be[c + 1] - m1 * a1;
    float p0 = fmaxf(__bfloat162float(hv.x) * a0 + b0, 0.f);
    float p1 = fmaxf(__bfloat162float(hv.y) * a1 + b1, 0.f);
    float acc0 = p0 * cw[c * 2] + p1 * cw[(c + 1) * 2];
    float acc1 = p0 * cw[c * 2 + 1] + p1 * cw[(c + 1) * 2 + 1];
    #pragma unroll
    for (int d = 32; d; d >>= 1) {
        acc0 += __shfl_down(acc0, d, 64);
        acc1 += __shfl_down(acc1, d, 64);
    }
    if (lane == 0) {
        out[w * 2] = acc0 + cb[0];
        out[w * 2 + 1] = acc1 + cb[1];
    }
}

extern "C" void kernel_launch(void* const* d_in, const int* in_sizes, int n_in,
                              void* d_out, int out_size, void* d_ws, size_t ws_size,
                              hipStream_t stream) {
    const float* x    = (const float*)d_in[0];
    const int*   ei   = (const int*)d_in[1];
    const int*   et   = (const int*)d_in[2];
    const float* w1   = (const float*)d_in[3];
    const float* root1= (const float*)d_in[4];
    const float* b1   = (const float*)d_in[5];
    const float* g1   = (const float*)d_in[6];
    const float* be1  = (const float*)d_in[7];
    const float* w2   = (const float*)d_in[8];
    const float* root2= (const float*)d_in[9];
    const float* b2   = (const float*)d_in[10];
    const float* g2   = (const float*)d_in[11];
    const float* be2  = (const float*)d_in[12];
    const float* cw   = (const float*)d_in[13];
    const float* cb   = (const float*)d_in[14];
    float* out = (float*)d_out;

    char* ws = (char*)d_ws;
    size_t off = 0;
    auto alloc = [&](size_t bytes) -> char* {
        char* p = ws + off;
        off += (bytes + 255) & ~(size_t)255;
        return p;
    };
    // zeroed region first
    int*   cnt     = (int*)alloc((size_t)NRSEG * 4);
    int*   fillcur = (int*)alloc((size_t)NRSEG * 4);
    int*   cursor  = (int*)alloc(256);
    float* stats1  = (float*)alloc(1024);
    float* stats2  = (float*)alloc(1024);
    size_t zero_bytes = off;
    int*   offs    = (int*)alloc((size_t)NRSEG * 4);
    __hip_bfloat16* Bt1 = (__hip_bfloat16*)alloc((size_t)DIM * KTOT * 2);
    __hip_bfloat16* Bt2 = (__hip_bfloat16*)alloc((size_t)DIM * KTOT * 2);
    int*   sorted  = (int*)alloc((size_t)N_EDGES * 4);
    __hip_bfloat16* xb = (__hip_bfloat16*)alloc((size_t)N_NODES * DIM * 2);
    __hip_bfloat16* h1 = (__hip_bfloat16*)alloc((size_t)N_NODES * DIM * 2);
    __hip_bfloat16* h2 = (__hip_bfloat16*)alloc((size_t)N_NODES * DIM * 2);

    hipMemsetAsync(d_ws, 0, zero_bytes, stream);

    k_hist<<<(N_EDGES + 255) / 256, 256, 0, stream>>>(ei, et, cnt);
    k_alloc<<<(NRSEG + 255) / 256, 256, 0, stream>>>(cnt, offs, cursor);
    k_fill<<<(N_EDGES + 255) / 256, 256, 0, stream>>>(ei, et, offs, fillcur, sorted);
    k_wconv2<<<2 * DIM * KTOT / 256, 256, 0, stream>>>(w1, root1, Bt1, w2, root2, Bt2);

    int fgrid = (N_NODES + TILE - 1) / TILE;   // 1563

    // layer 1
    k_cast<<<(N_NODES * DIM / 4 + 255) / 256, 256, 0, stream>>>(x, xb);
    k_fusedC<<<fgrid, 256, 0, stream>>>(xb, cnt, offs, sorted, Bt1, b1, h1, stats1);

    // layer 2
    k_castbn2<<<(N_NODES * DIM / 8 + 255) / 256, 256, 0, stream>>>(h1, stats1, g1, be1, xb);
    k_fusedC<<<fgrid, 256, 0, stream>>>(xb, cnt, offs, sorted, Bt2, b2, h2, stats2);

    k_classifier<<<(N_NODES + 3) / 4, 256, 0, stream>>>(h2, stats2, g2, be2, cw, cb, out);
}

// Round 11
// 505.260 us; speedup vs baseline: 1.2688x; 1.0262x over previous
//
#include <hip/hip_runtime.h>
#include <hip/hip_bf16.h>

#define N_NODES 50000
#define N_EDGES 800000
#define DIM 128
#define NREL 8
#define KTOT 1152              // (NREL+1)*DIM
#define NRSEG (N_NODES * NREL) // 400000
#define BN_EPS 1e-5f
#define TILE 32                // nodes per block
#define ASTRIDE 136            // LDS row stride elems (272 B -> conflict floor)

typedef __attribute__((ext_vector_type(8))) short bf16x8;
typedef __attribute__((ext_vector_type(16))) float f32x16;

__device__ inline float b2f(short s) {
    union { unsigned u; float f; } t;
    t.u = ((unsigned)(unsigned short)s) << 16;
    return t.f;
}
__device__ inline short f2b(float f) {
    __hip_bfloat16 h = __float2bfloat16(f);
    return *reinterpret_cast<short*>(&h);
}

// ---------------- CSR build ----------------

__global__ void k_hist(const int* __restrict__ ei, const int* __restrict__ et,
                       int* __restrict__ cnt) {
    int e = blockIdx.x * 256 + threadIdx.x;
    if (e < N_EDGES) {
        int tgt = ei[N_EDGES + e];
        int r = et[e];
        atomicAdd(&cnt[tgt * NREL + r], 1);
    }
}

__global__ void k_alloc(const int* __restrict__ cnt, int* __restrict__ offs,
                        int* __restrict__ cursor) {
    int i = blockIdx.x * 256 + threadIdx.x;
    int lane = threadIdx.x & 63;
    int c = (i < NRSEG) ? cnt[i] : 0;
    int incl = c;
    #pragma unroll
    for (int d = 1; d < 64; d <<= 1) {
        int t = __shfl_up(incl, d, 64);
        if (lane >= d) incl += t;
    }
    int total = __shfl(incl, 63, 64);
    int base = 0;
    if (lane == 63) base = atomicAdd(cursor, total);
    base = __shfl(base, 63, 64);
    if (i < NRSEG) offs[i] = base + incl - c;
}

__global__ void k_fill(const int* __restrict__ ei, const int* __restrict__ et,
                       const int* __restrict__ offs, int* __restrict__ fillcur,
                       int* __restrict__ sorted) {
    int e = blockIdx.x * 256 + threadIdx.x;
    if (e < N_EDGES) {
        int src = ei[e];
        int tgt = ei[N_EDGES + e];
        int comp = tgt * NREL + et[e];
        int pos = atomicAdd(&fillcur[comp], 1);
        sorted[offs[comp] + pos] = src;
    }
}

// ---------------- weight conversion (both layers in one launch)
__global__ void k_wconv2(const float* __restrict__ W1, const float* __restrict__ root1,
                         __hip_bfloat16* __restrict__ Bt1,
                         const float* __restrict__ W2, const float* __restrict__ root2,
                         __hip_bfloat16* __restrict__ Bt2) {
    int gidx = blockIdx.x * 256 + threadIdx.x;
    int which = gidx >= DIM * KTOT;
    int idx = which ? gidx - DIM * KTOT : gidx;
    const float* W = which ? W2 : W1;
    const float* root = which ? root2 : root1;
    __hip_bfloat16* Bt = which ? Bt2 : Bt1;
    int o = idx / KTOT, k = idx % KTOT;
    float v;
    if (k < NREL * DIM) {
        int r = k >> 7, i = k & 127;
        v = W[(r * DIM + i) * DIM + o];
    } else {
        int i = k - NREL * DIM;
        v = root[i * DIM + o];
    }
    Bt[idx] = __float2bfloat16(v);
}

// ---------------- cast fp32 input -> bf16
__global__ void k_cast(const float* __restrict__ in, __hip_bfloat16* __restrict__ out) {
    int i = (blockIdx.x * 256 + threadIdx.x) * 4;
    if (i >= N_NODES * DIM) return;
    float4 v = *(const float4*)&in[i];
    short4 o;
    o.x = f2b(v.x); o.y = f2b(v.y); o.z = f2b(v.z); o.w = f2b(v.w);
    *(short4*)&out[i] = o;
}

// ---------------- fused RGCN layer (v4): 32-node tile, branchless dual-chain
// interleaved gather (4 idx + 4 row loads in flight per thread), optional
// fused BN+ReLU on the gathered input (template<BN>). Per K-slice r:
// stage At[32][128] bf16 in LDS, barrier, 4 waves x 32x32 MFMA vs Bt, barrier.
// Epilogue: bias, bf16 h write, BN-stat atomics.
// MFMA 32x32x16: A-frag lane l: row=l&31, k=(l>>5)*8+j; B-frag: col=l&31,
// same k. C/D: col=lane&31, row=(reg&3)+8*(reg>>2)+4*(lane>>5).
template<int BN>
__global__ __launch_bounds__(256) void k_fusedD(
        const __hip_bfloat16* __restrict__ xb,
        const int* __restrict__ cnt, const int* __restrict__ offs,
        const int* __restrict__ sorted,
        const __hip_bfloat16* __restrict__ Bt,
        const float* __restrict__ bias,
        const float* __restrict__ bnstats, const float* __restrict__ g,
        const float* __restrict__ be,
        __hip_bfloat16* __restrict__ h, float* __restrict__ stats) {
    __shared__ __hip_bfloat16 At[TILE * ASTRIDE];   // 8704 B
    __shared__ int cntS[TILE][NREL];
    __shared__ int offS[TILE][NREL];
    int tid = threadIdx.x;
    int n0 = blockIdx.x * TILE;

    // CSR meta: thread t -> node t>>3, rel t&7
    {
        int ni = tid >> 3, r = tid & 7;
        int node = n0 + ni;
        int c = 0, o = 0;
        if (node < N_NODES) {
            c = cnt[node * NREL + r];
            o = offs[node * NREL + r];
        }
        cntS[ni][r] = c;
        offS[ni][r] = o;
    }

    // mfma role indices
    int lane = tid & 63, wid = tid >> 6;
    int half = lane >> 5, l31 = lane & 31;
    const __hip_bfloat16* bBase = Bt + (size_t)(wid * 32 + l31) * KTOT + half * 8;
    f32x16 acc = {};

    // stage role: node pair (spn, spn+16), channel group sub (8 ch each)
    int spn = tid >> 4, sub = tid & 15;
    const __hip_bfloat16* xsub = xb + sub * 8;

    // BN coefficients for this thread's 8 stage channels
    float aC[8], bC[8];
    if (BN) {
        const float invn = 1.f / (float)N_NODES;
        #pragma unroll
        for (int j = 0; j < 8; ++j) {
            int ch = sub * 8 + j;
            float m = bnstats[ch] * invn;
            float var = bnstats[128 + ch] * invn - m * m;
            float aa = g[ch] * rsqrtf(var + BN_EPS);
            aC[j] = aa;
            bC[j] = be[ch] - m * aa;
        }
    }
    __syncthreads();

    #pragma unroll 1
    for (int r = 0; r < 9; ++r) {
        if (r < 8) {
            int cA = cntS[spn][r],      oA = offS[spn][r];
            int cB = cntS[spn + 16][r], oB = offS[spn + 16][r];
            float sA[8] = {0.f,0.f,0.f,0.f,0.f,0.f,0.f,0.f};
            float sB[8] = {0.f,0.f,0.f,0.f,0.f,0.f,0.f,0.f};
            int mx = max(cA, cB);
            #pragma unroll 1
            for (int i = 0; i < mx; i += 2) {
                // unconditional idx loads (sorted is padded); clamp invalid to 0
                int ja0 = sorted[oA + i];
                int ja1 = sorted[oA + i + 1];
                int jb0 = sorted[oB + i];
                int jb1 = sorted[oB + i + 1];
                bool vA0 = i < cA, vA1 = i + 1 < cA;
                bool vB0 = i < cB, vB1 = i + 1 < cB;
                int ia0 = vA0 ? ja0 : 0;
                int ia1 = vA1 ? ja1 : 0;
                int ib0 = vB0 ? jb0 : 0;
                int ib1 = vB1 ? jb1 : 0;
                bf16x8 ra0 = *(const bf16x8*)(xsub + (size_t)ia0 * DIM);
                bf16x8 ra1 = *(const bf16x8*)(xsub + (size_t)ia1 * DIM);
                bf16x8 rb0 = *(const bf16x8*)(xsub + (size_t)ib0 * DIM);
                bf16x8 rb1 = *(const bf16x8*)(xsub + (size_t)ib1 * DIM);
                float ma0 = vA0 ? 1.f : 0.f, ma1 = vA1 ? 1.f : 0.f;
                float mb0 = vB0 ? 1.f : 0.f, mb1 = vB1 ? 1.f : 0.f;
                #pragma unroll
                for (int j = 0; j < 8; ++j) {
                    float e;
                    e = b2f(ra0[j]); if (BN) e = fmaxf(fmaf(aC[j], e, bC[j]), 0.f);
                    sA[j] = fmaf(ma0, e, sA[j]);
                    e = b2f(ra1[j]); if (BN) e = fmaxf(fmaf(aC[j], e, bC[j]), 0.f);
                    sA[j] = fmaf(ma1, e, sA[j]);
                    e = b2f(rb0[j]); if (BN) e = fmaxf(fmaf(aC[j], e, bC[j]), 0.f);
                    sB[j] = fmaf(mb0, e, sB[j]);
                    e = b2f(rb1[j]); if (BN) e = fmaxf(fmaf(aC[j], e, bC[j]), 0.f);
                    sB[j] = fmaf(mb1, e, sB[j]);
                }
            }
            float invA = (cA > 0) ? 1.f / (float)cA : 0.f;
            float invB = (cB > 0) ? 1.f / (float)cB : 0.f;
            bf16x8 ovA, ovB;
            #pragma unroll
            for (int j = 0; j < 8; ++j) {
                ovA[j] = f2b(sA[j] * invA);
                ovB[j] = f2b(sB[j] * invB);
            }
            *(bf16x8*)&At[spn * ASTRIDE + sub * 8] = ovA;
            *(bf16x8*)&At[(spn + 16) * ASTRIDE + sub * 8] = ovB;
        } else {
            // self slice: nodes spn and spn+16
            #pragma unroll
            for (int p = 0; p < 2; ++p) {
                int ni = spn + p * 16;
                int node = n0 + ni;
                bf16x8 sv = {};
                if (node < N_NODES) sv = *(const bf16x8*)(xsub + (size_t)node * DIM);
                if (BN) {
                    #pragma unroll
                    for (int j = 0; j < 8; ++j)
                        sv[j] = f2b(fmaxf(fmaf(aC[j], b2f(sv[j]), bC[j]), 0.f));
                    if (node >= N_NODES) sv = bf16x8{};
                }
                *(bf16x8*)&At[ni * ASTRIDE + sub * 8] = sv;
            }
        }
        __syncthreads();
        // mfma phase: K=128 slice r; wave wid owns cols wid*32..+32
        const __hip_bfloat16* bs = bBase + r * DIM;
        #pragma unroll
        for (int m = 0; m < 8; ++m) {
            bf16x8 a = *(const bf16x8*)&At[l31 * ASTRIDE + m * 16 + half * 8];
            bf16x8 b = *(const bf16x8*)(bs + m * 16);
            acc = __builtin_amdgcn_mfma_f32_32x32x16_bf16(a, b, acc, 0, 0, 0);
        }
        __syncthreads();
    }

    // epilogue: bias, store h (bf16), BN stats
    int col = wid * 32 + l31;
    float bv = bias[col];
    float s1 = 0.f, s2 = 0.f;
    #pragma unroll
    for (int reg = 0; reg < 16; ++reg) {
        int row = n0 + (reg & 3) + 8 * (reg >> 2) + 4 * half;
        float v = acc[reg] + bv;
        if (row < N_NODES) {
            h[(size_t)row * DIM + col] = __float2bfloat16(v);
            s1 += v; s2 += v * v;
        }
    }
    s1 += __shfl_xor(s1, 32, 64);
    s2 += __shfl_xor(s2, 32, 64);
    if (half == 0) {
        atomicAdd(&stats[col], s1);
        atomicAdd(&stats[128 + col], s2);
    }
}

// ---------------- classifier: out[v,0:2] = relu(bn(h2[v])) @ cw + cb, bn inline
__global__ void k_classifier(const __hip_bfloat16* __restrict__ h, const float* __restrict__ stats,
                             const float* __restrict__ g, const float* __restrict__ be,
                             const float* __restrict__ cw, const float* __restrict__ cb,
                             float* __restrict__ out) {
    int w = blockIdx.x * 4 + (threadIdx.x >> 6);
    int lane = threadIdx.x & 63;
    if (w >= N_NODES) return;
    int c = lane * 2;
    const float invn = 1.f / (float)N_NODES;
    __hip_bfloat162 hv = *(const __hip_bfloat162*)&h[(size_t)w * DIM + c];
    float m0 = stats[c] * invn, var0 = stats[128 + c] * invn - m0 * m0;
    float a0 = g[c] * rsqrtf(var0 + BN_EPS), b0 = be[c] - m0 * a0;
    float m1 = stats[c + 1] * invn, var1 = stats[128 + c + 1] * invn - m1 * m1;
    float a1 = g[c + 1] * rsqrtf(var1 + BN_EPS), b1 = be[c + 1] - m1 * a1;
    float p0 = fmaxf(__bfloat162float(hv.x) * a0 + b0, 0.f);
    float p1 = fmaxf(__bfloat162float(hv.y) * a1 + b1, 0.f);
    float acc0 = p0 * cw[c * 2] + p1 * cw[(c + 1) * 2];
    float acc1 = p0 * cw[c * 2 + 1] + p1 * cw[(c + 1) * 2 + 1];
    #pragma unroll
    for (int d = 32; d; d >>= 1) {
        acc0 += __shfl_down(acc0, d, 64);
        acc1 += __shfl_down(acc1, d, 64);
    }
    if (lane == 0) {
        out[w * 2] = acc0 + cb[0];
        out[w * 2 + 1] = acc1 + cb[1];
    }
}

extern "C" void kernel_launch(void* const* d_in, const int* in_sizes, int n_in,
                              void* d_out, int out_size, void* d_ws, size_t ws_size,
                              hipStream_t stream) {
    const float* x    = (const float*)d_in[0];
    const int*   ei   = (const int*)d_in[1];
    const int*   et   = (const int*)d_in[2];
    const float* w1   = (const float*)d_in[3];
    const float* root1= (const float*)d_in[4];
    const float* b1   = (const float*)d_in[5];
    const float* g1   = (const float*)d_in[6];
    const float* be1  = (const float*)d_in[7];
    const float* w2   = (const float*)d_in[8];
    const float* root2= (const float*)d_in[9];
    const float* b2   = (const float*)d_in[10];
    const float* g2   = (const float*)d_in[11];
    const float* be2  = (const float*)d_in[12];
    const float* cw   = (const float*)d_in[13];
    const float* cb   = (const float*)d_in[14];
    float* out = (float*)d_out;

    char* ws = (char*)d_ws;
    size_t off = 0;
    auto alloc = [&](size_t bytes) -> char* {
        char* p = ws + off;
        off += (bytes + 255) & ~(size_t)255;
        return p;
    };
    // zeroed region first
    int*   cnt     = (int*)alloc((size_t)NRSEG * 4);
    int*   fillcur = (int*)alloc((size_t)NRSEG * 4);
    int*   cursor  = (int*)alloc(256);
    float* stats1  = (float*)alloc(1024);
    float* stats2  = (float*)alloc(1024);
    size_t zero_bytes = off;
    int*   offs    = (int*)alloc((size_t)NRSEG * 4);
    __hip_bfloat16* Bt1 = (__hip_bfloat16*)alloc((size_t)DIM * KTOT * 2);
    __hip_bfloat16* Bt2 = (__hip_bfloat16*)alloc((size_t)DIM * KTOT * 2);
    int*   sorted  = (int*)alloc((size_t)N_EDGES * 4 + 1024);  // +pad for unconditional loads
    __hip_bfloat16* xb = (__hip_bfloat16*)alloc((size_t)N_NODES * DIM * 2);
    __hip_bfloat16* h1 = (__hip_bfloat16*)alloc((size_t)N_NODES * DIM * 2);
    __hip_bfloat16* h2 = (__hip_bfloat16*)alloc((size_t)N_NODES * DIM * 2);

    hipMemsetAsync(d_ws, 0, zero_bytes, stream);

    k_hist<<<(N_EDGES + 255) / 256, 256, 0, stream>>>(ei, et, cnt);
    k_alloc<<<(NRSEG + 255) / 256, 256, 0, stream>>>(cnt, offs, cursor);
    k_fill<<<(N_EDGES + 255) / 256, 256, 0, stream>>>(ei, et, offs, fillcur, sorted);
    k_wconv2<<<2 * DIM * KTOT / 256, 256, 0, stream>>>(w1, root1, Bt1, w2, root2, Bt2);

    int fgrid = (N_NODES + TILE - 1) / TILE;   // 1563

    // layer 1 (no BN on input)
    k_cast<<<(N_NODES * DIM / 4 + 255) / 256, 256, 0, stream>>>(x, xb);
    k_fusedD<0><<<fgrid, 256, 0, stream>>>(xb, cnt, offs, sorted, Bt1, b1,
                                           nullptr, nullptr, nullptr, h1, stats1);

    // layer 2 (BN1+ReLU fused into gather, reads h1 directly)
    k_fusedD<1><<<fgrid, 256, 0, stream>>>(h1, cnt, offs, sorted, Bt2, b2,
                                           stats1, g1, be1, h2, stats2);

    k_classifier<<<(N_NODES + 3) / 4, 256, 0, stream>>>(h2, stats2, g2, be2, cw, cb, out);
}